// Round 5
// baseline (219.021 us; speedup 1.0000x reference)
//
#include <hip/hip_runtime.h>
#include <hip/hip_bf16.h>

#define B_ 16
#define L_ 2048
#define D_ 1024
#define S_ 32

// ---------------- Kernel A: per-example length bucket ----------------
__global__ __launch_bounds__(256) void lengths_kernel(const int* __restrict__ mask,
                                                      int* __restrict__ lbuck) {
    const int b = blockIdx.x;
    const int t = threadIdx.x;
    int s = 0;
    for (int i = t; i < L_; i += 256) s += mask[b * L_ + i];
#pragma unroll
    for (int off = 32; off > 0; off >>= 1) s += __shfl_down(s, off, 64);
    __shared__ int red[4];
    if ((t & 63) == 0) red[t >> 6] = s;
    __syncthreads();
    if (t == 0) {
        int tot = red[0] + red[1] + red[2] + red[3];
        int lb = tot / 32;                 // LEN_BUCKET = 32
        if (lb < 0) lb = 0;
        if (lb > 63) lb = 63;
        lbuck[b] = lb;
    }
}

// ---------------- Kernel B: fused span-mean + classifier head ----------------
// All tensors fp32. One block per (b,s) span; 256 threads x float4 = one full
// 1024-dim row per coalesced load. Logits written fp32 directly into d_out.
__global__ __launch_bounds__(256) void span_logits_kernel(
        const float* __restrict__ enc,
        const int* __restrict__ head,
        const int* __restrict__ tail,
        const float* __restrict__ wemb,
        const float* __restrict__ lemb,
        const float* __restrict__ cls_w,
        const float* __restrict__ cls_b,
        const int* __restrict__ lbuck,
        float* __restrict__ out) {
    const int bs = blockIdx.x;            // 0..511
    const int b  = bs / S_;
    const int t  = threadIdx.x;
    const int h  = head[bs];
    const int tl = tail[bs];
    int lo = h + 1; if (lo < 0) lo = 0;
    int hi = tl;    if (hi > L_) hi = L_;
    const int nrow = hi - lo;

    const int dc = t * 4;                 // dim chunk base (4 fp32 = 16 B)

    // preload this thread's 4x3 weight block
    float w00 = cls_w[(dc + 0) * 3 + 0], w01 = cls_w[(dc + 0) * 3 + 1], w02 = cls_w[(dc + 0) * 3 + 2];
    float w10 = cls_w[(dc + 1) * 3 + 0], w11 = cls_w[(dc + 1) * 3 + 1], w12 = cls_w[(dc + 1) * 3 + 2];
    float w20 = cls_w[(dc + 2) * 3 + 0], w21 = cls_w[(dc + 2) * 3 + 1], w22 = cls_w[(dc + 2) * 3 + 2];
    float w30 = cls_w[(dc + 3) * 3 + 0], w31 = cls_w[(dc + 3) * 3 + 1], w32 = cls_w[(dc + 3) * 3 + 2];

    float a0 = 0.f, a1 = 0.f, a2 = 0.f;
    const float* base = enc + (size_t)b * (L_ * D_) + dc;
    for (int l = lo; l < hi; ++l) {
        const float4 u = *reinterpret_cast<const float4*>(base + (size_t)l * D_);
        a0 = fmaf(u.x, w00, a0); a1 = fmaf(u.x, w01, a1); a2 = fmaf(u.x, w02, a2);
        a0 = fmaf(u.y, w10, a0); a1 = fmaf(u.y, w11, a1); a2 = fmaf(u.y, w12, a2);
        a0 = fmaf(u.z, w20, a0); a1 = fmaf(u.z, w21, a1); a2 = fmaf(u.z, w22, a2);
        a0 = fmaf(u.w, w30, a0); a1 = fmaf(u.w, w31, a1); a2 = fmaf(u.w, w32, a2);
    }

    // reduce 3 accumulators across 256 threads
#pragma unroll
    for (int off = 32; off > 0; off >>= 1) {
        a0 += __shfl_down(a0, off, 64);
        a1 += __shfl_down(a1, off, 64);
        a2 += __shfl_down(a2, off, 64);
    }
    __shared__ float sred[12];
    const int wv = t >> 6;
    if ((t & 63) == 0) { sred[wv * 3 + 0] = a0; sred[wv * 3 + 1] = a1; sred[wv * 3 + 2] = a2; }
    __syncthreads();

    if (t == 0) {
        float r0 = sred[0] + sred[3] + sred[6] + sred[9];
        float r1 = sred[1] + sred[4] + sred[7] + sred[10];
        float r2 = sred[2] + sred[5] + sred[8] + sred[11];
        float cnt = (float)(nrow > 0 ? nrow : 0);
        if (cnt < 1.f) cnt = 1.f;
        const float inv = 1.f / cnt;
        r0 *= inv; r1 *= inv; r2 *= inv;

        // width-bucket + length-bucket embedding contributions
        int wb = (tl - h) / 16;           // WIDTH_BUCKET = 16
        if (wb < 0) wb = 0;
        if (wb > 63) wb = 63;
        const int lb = lbuck[b];
        const float* we = wemb + wb * 8;
        const float* le = lemb + lb * 8;
#pragma unroll
        for (int j = 0; j < 8; ++j) {
            const float wvf = we[j];
            const float lvf = le[j];
            r0 += wvf * cls_w[(D_ + j) * 3 + 0] + lvf * cls_w[(D_ + 8 + j) * 3 + 0];
            r1 += wvf * cls_w[(D_ + j) * 3 + 1] + lvf * cls_w[(D_ + 8 + j) * 3 + 1];
            r2 += wvf * cls_w[(D_ + j) * 3 + 2] + lvf * cls_w[(D_ + 8 + j) * 3 + 2];
        }
        r0 += cls_b[0];
        r1 += cls_b[1];
        r2 += cls_b[2];

        out[bs * 3 + 0] = r0;
        out[bs * 3 + 1] = r1;
        out[bs * 3 + 2] = r2;
    }
}

// ---------------- Kernel C: cross-entropy over 512 spans ----------------
__global__ __launch_bounds__(512) void ce_kernel(const float* __restrict__ logits,
                                                 const int* __restrict__ labels,
                                                 float* __restrict__ out) {
    const int i = threadIdx.x;            // 0..511, one per (b,s)
    const int lab = labels[i];
    const float l0 = logits[i * 3 + 0];
    const float l1 = logits[i * 3 + 1];
    const float l2 = logits[i * 3 + 2];
    const float m  = fmaxf(l0, fmaxf(l1, l2));
    const float lse = m + logf(expf(l0 - m) + expf(l1 - m) + expf(l2 - m));
    int cl = lab < 0 ? 0 : (lab > 2 ? 2 : lab);
    const float pick = (cl == 0) ? l0 : ((cl == 1) ? l1 : l2);
    float nll = 0.f, val = 0.f;
    if (lab > -1) { nll = lse - pick; val = 1.f; }
#pragma unroll
    for (int off = 32; off > 0; off >>= 1) {
        nll += __shfl_down(nll, off, 64);
        val += __shfl_down(val, off, 64);
    }
    __shared__ float rn[8], rv[8];
    const int wv = i >> 6;
    if ((i & 63) == 0) { rn[wv] = nll; rv[wv] = val; }
    __syncthreads();
    if (i == 0) {
        float sn = 0.f, sv = 0.f;
#pragma unroll
        for (int k = 0; k < 8; ++k) { sn += rn[k]; sv += rv[k]; }
        out[B_ * S_ * 3] = sn / fmaxf(sv, 1.f);
    }
}

extern "C" void kernel_launch(void* const* d_in, const int* in_sizes, int n_in,
                              void* d_out, int out_size, void* d_ws, size_t ws_size,
                              hipStream_t stream) {
    const float* enc    = (const float*)d_in[0];
    const int*   mask   = (const int*)d_in[1];
    const int*   head   = (const int*)d_in[2];
    const int*   tail   = (const int*)d_in[3];
    const int*   labels = (const int*)d_in[4];
    const float* wemb   = (const float*)d_in[5];
    const float* lemb   = (const float*)d_in[6];
    const float* cls_w  = (const float*)d_in[7];
    const float* cls_b  = (const float*)d_in[8];
    float* out = (float*)d_out;           // [B*S*3 logits] + [1 ce_loss], fp32

    int* lbuck = (int*)d_ws;

    lengths_kernel<<<B_, 256, 0, stream>>>(mask, lbuck);
    span_logits_kernel<<<B_ * S_, 256, 0, stream>>>(enc, head, tail, wemb, lemb,
                                                    cls_w, cls_b, lbuck, out);
    ce_kernel<<<1, 512, 0, stream>>>(out, labels, out);
}

// Round 6
// 206.402 us; speedup vs baseline: 1.0611x; 1.0611x over previous
//
#include <hip/hip_runtime.h>
#include <hip/hip_bf16.h>

#define B_ 16
#define L_ 2048
#define D_ 1024
#define S_ 32

// ---------------- Kernel B: fused lengths + span-mean + classifier head ----------------
// All tensors fp32. One block per (b,s) span; 1024 threads = 4 row-slots x 256
// dim-chunks (float4, 16 B/lane coalesced). 512 blocks = 2 blocks/CU x 16 waves
// = 32 waves/CU (full occupancy). Each block also redundantly reduces its
// example's attention-mask sum (monotone mask; +8 KB L2-hot reads per block).
__global__ __launch_bounds__(1024) void span_logits_kernel(
        const float* __restrict__ enc,
        const int* __restrict__ mask,
        const int* __restrict__ head,
        const int* __restrict__ tail,
        const float* __restrict__ wemb,
        const float* __restrict__ lemb,
        const float* __restrict__ cls_w,
        const float* __restrict__ cls_b,
        float* __restrict__ out) {
    const int bs = blockIdx.x;            // 0..511
    const int b  = bs / S_;
    const int t  = threadIdx.x;           // 0..1023
    const int h  = head[bs];
    const int tl = tail[bs];
    int lo = h + 1; if (lo < 0) lo = 0;
    int hi = tl;    if (hi > L_) hi = L_;
    const int nrow = hi - lo;

    const int rg = t >> 8;                // row-slot 0..3
    const int dc = (t & 255) * 4;         // dim chunk base (4 fp32 = 16 B)

    // --- mask partial sum (2 ints per thread, 8B coalesced) ---
    const int2 mk = reinterpret_cast<const int2*>(mask + b * L_)[t];
    int msum = mk.x + mk.y;

    // preload this thread's 4x3 weight block
    const float w00 = cls_w[(dc + 0) * 3 + 0], w01 = cls_w[(dc + 0) * 3 + 1], w02 = cls_w[(dc + 0) * 3 + 2];
    const float w10 = cls_w[(dc + 1) * 3 + 0], w11 = cls_w[(dc + 1) * 3 + 1], w12 = cls_w[(dc + 1) * 3 + 2];
    const float w20 = cls_w[(dc + 2) * 3 + 0], w21 = cls_w[(dc + 2) * 3 + 1], w22 = cls_w[(dc + 2) * 3 + 2];
    const float w30 = cls_w[(dc + 3) * 3 + 0], w31 = cls_w[(dc + 3) * 3 + 1], w32 = cls_w[(dc + 3) * 3 + 2];

    float a0 = 0.f, a1 = 0.f, a2 = 0.f;
    const float* base = enc + (size_t)b * (L_ * D_) + dc;
    for (int l = lo + rg; l < hi; l += 4) {
        const float4 u = *reinterpret_cast<const float4*>(base + (size_t)l * D_);
        a0 = fmaf(u.x, w00, a0); a1 = fmaf(u.x, w01, a1); a2 = fmaf(u.x, w02, a2);
        a0 = fmaf(u.y, w10, a0); a1 = fmaf(u.y, w11, a1); a2 = fmaf(u.y, w12, a2);
        a0 = fmaf(u.z, w20, a0); a1 = fmaf(u.z, w21, a1); a2 = fmaf(u.z, w22, a2);
        a0 = fmaf(u.w, w30, a0); a1 = fmaf(u.w, w31, a1); a2 = fmaf(u.w, w32, a2);
    }

    // wave-level reduction of 3 accumulators + mask sum
#pragma unroll
    for (int off = 32; off > 0; off >>= 1) {
        a0 += __shfl_down(a0, off, 64);
        a1 += __shfl_down(a1, off, 64);
        a2 += __shfl_down(a2, off, 64);
        msum += __shfl_down(msum, off, 64);
    }
    __shared__ float sred[16 * 3];
    __shared__ int   slen[16];
    const int wv = t >> 6;                // wave id 0..15
    if ((t & 63) == 0) {
        sred[wv * 3 + 0] = a0;
        sred[wv * 3 + 1] = a1;
        sred[wv * 3 + 2] = a2;
        slen[wv] = msum;
    }
    __syncthreads();

    if (t == 0) {
        float r0 = 0.f, r1 = 0.f, r2 = 0.f;
        int len = 0;
#pragma unroll
        for (int k = 0; k < 16; ++k) {
            r0 += sred[k * 3 + 0];
            r1 += sred[k * 3 + 1];
            r2 += sred[k * 3 + 2];
            len += slen[k];
        }
        float cnt = (float)(nrow > 0 ? nrow : 0);
        if (cnt < 1.f) cnt = 1.f;
        const float inv = 1.f / cnt;
        r0 *= inv; r1 *= inv; r2 *= inv;

        // width-bucket embedding contribution
        int wb = (tl - h) / 16;           // WIDTH_BUCKET = 16
        if (wb < 0) wb = 0;
        if (wb > 63) wb = 63;
        // length-bucket embedding contribution
        int lb = len / 32;                // LEN_BUCKET = 32
        if (lb < 0) lb = 0;
        if (lb > 63) lb = 63;
        const float* we = wemb + wb * 8;
        const float* le = lemb + lb * 8;
#pragma unroll
        for (int j = 0; j < 8; ++j) {
            const float wvf = we[j];
            const float lvf = le[j];
            r0 += wvf * cls_w[(D_ + j) * 3 + 0] + lvf * cls_w[(D_ + 8 + j) * 3 + 0];
            r1 += wvf * cls_w[(D_ + j) * 3 + 1] + lvf * cls_w[(D_ + 8 + j) * 3 + 1];
            r2 += wvf * cls_w[(D_ + j) * 3 + 2] + lvf * cls_w[(D_ + 8 + j) * 3 + 2];
        }
        r0 += cls_b[0];
        r1 += cls_b[1];
        r2 += cls_b[2];

        out[bs * 3 + 0] = r0;
        out[bs * 3 + 1] = r1;
        out[bs * 3 + 2] = r2;
    }
}

// ---------------- Kernel C: cross-entropy over 512 spans ----------------
__global__ __launch_bounds__(512) void ce_kernel(const float* __restrict__ logits,
                                                 const int* __restrict__ labels,
                                                 float* __restrict__ out) {
    const int i = threadIdx.x;            // 0..511, one per (b,s)
    const int lab = labels[i];
    const float l0 = logits[i * 3 + 0];
    const float l1 = logits[i * 3 + 1];
    const float l2 = logits[i * 3 + 2];
    const float m  = fmaxf(l0, fmaxf(l1, l2));
    const float lse = m + logf(expf(l0 - m) + expf(l1 - m) + expf(l2 - m));
    int cl = lab < 0 ? 0 : (lab > 2 ? 2 : lab);
    const float pick = (cl == 0) ? l0 : ((cl == 1) ? l1 : l2);
    float nll = 0.f, val = 0.f;
    if (lab > -1) { nll = lse - pick; val = 1.f; }
#pragma unroll
    for (int off = 32; off > 0; off >>= 1) {
        nll += __shfl_down(nll, off, 64);
        val += __shfl_down(val, off, 64);
    }
    __shared__ float rn[8], rv[8];
    const int wv = i >> 6;
    if ((i & 63) == 0) { rn[wv] = nll; rv[wv] = val; }
    __syncthreads();
    if (i == 0) {
        float sn = 0.f, sv = 0.f;
#pragma unroll
        for (int k = 0; k < 8; ++k) { sn += rn[k]; sv += rv[k]; }
        out[B_ * S_ * 3] = sn / fmaxf(sv, 1.f);
    }
}

extern "C" void kernel_launch(void* const* d_in, const int* in_sizes, int n_in,
                              void* d_out, int out_size, void* d_ws, size_t ws_size,
                              hipStream_t stream) {
    const float* enc    = (const float*)d_in[0];
    const int*   mask   = (const int*)d_in[1];
    const int*   head   = (const int*)d_in[2];
    const int*   tail   = (const int*)d_in[3];
    const int*   labels = (const int*)d_in[4];
    const float* wemb   = (const float*)d_in[5];
    const float* lemb   = (const float*)d_in[6];
    const float* cls_w  = (const float*)d_in[7];
    const float* cls_b  = (const float*)d_in[8];
    float* out = (float*)d_out;           // [B*S*3 logits] + [1 ce_loss], fp32

    span_logits_kernel<<<B_ * S_, 1024, 0, stream>>>(enc, mask, head, tail, wemb, lemb,
                                                     cls_w, cls_b, out);
    ce_kernel<<<1, 512, 0, stream>>>(out, labels, out);
}